// Round 10
// baseline (301.512 us; speedup 1.0000x reference)
//
#include <hip/hip_runtime.h>

// ChebyKANLayer: y[t,o] = bias[o] + sum_k A[t,k]*B[k,o], K=8192, k=i*8+(d-1), d=1..8.
// R10: 4 waves/SIMD. Block 128x64, 4 waves of 64x32, grid 1024 = 4 blocks/CU
// (R5's 64x64-wave config is capped at 2 waves/SIMD by total wave count).
// B via global_load_lds -> LDS dbuf (block-shared, 8KB/stage), single barrier/stage.
// A-frags in registers: stride-2 packed Chebyshev from thw seeds (R8's coalesced
// gather layout -- 2 dwordx4 per wave-stage, 2-stage-ahead prefetch).

typedef __bf16 bf16;
typedef __bf16 bf16x8 __attribute__((ext_vector_type(8)));
typedef float f32x2 __attribute__((ext_vector_type(2)));
typedef float f32x4 __attribute__((ext_vector_type(4)));
typedef float f32x16 __attribute__((ext_vector_type(16)));

__device__ __forceinline__ void g2lds16(const void* g, void* l) {
  __builtin_amdgcn_global_load_lds(
      (const __attribute__((address_space(1))) unsigned int*)g,
      (__attribute__((address_space(3))) unsigned int*)l, 16, 0, 0);
}

__device__ __forceinline__ float fast_tanh(float a) {
  float e = __expf(a + a);
  return 1.f - 2.f * __builtin_amdgcn_rcpf(e + 1.f);   // saturating, NaN-free
}

// ---- fused prep ----
// blocks [0,1024): Bt + bias partials.
//   Bt 16B-unit idx16 = ((nb*128 + s)*8 + c)*64 + col64 ; nb=o>>6, col64=o&63, s=i>>3, c=i&7.
// blocks [1024,1280): thw gather (R8-proven):
//   thw[((g*128+s)*64 + ln)*8 + mt*4 + ks] = tanh(x[g*64+mt*32+(ln&31)][s*8+2ks+(ln>>5)])
__global__ __launch_bounds__(256)
void cheby_prep(const float* __restrict__ x, const float* __restrict__ C,
                bf16* __restrict__ Bt, float* __restrict__ bias_p,
                float* __restrict__ thw) {
  const int bid = blockIdx.x, tid = threadIdx.x;
  if (bid >= 1024) {                               // ---- thw branch
    const int b2 = bid - 1024;
    const int g  = b2 >> 1;                        // 64-row group [0,128)
    const int sh = (b2 & 1) * 64;                  // stage half
    __shared__ float lt[64][65];
    for (int c8 = 0; c8 < 8; ++c8) {               // 8 tiles of 64 i-cols (8 stages each)
      const int i0 = sh * 8 + c8 * 64;
      __syncthreads();
      #pragma unroll
      for (int p = 0; p < 4; ++p) {                // coalesced read + tanh
        int idx = tid + p * 256;
        int row = idx >> 4, sg = idx & 15;
        f32x4 v = *(const f32x4*)(x + (size_t)(g * 64 + row) * 1024 + i0 + sg * 4);
        #pragma unroll
        for (int j = 0; j < 4; ++j) lt[row][sg * 4 + j] = fast_tanh(v[j]);
      }
      __syncthreads();
      #pragma unroll
      for (int half = 0; half < 2; ++half) {       // coalesced gather-layout write
        int slot = tid + half * 256;
        int js = slot >> 6, ln = slot & 63;
        int ml = ln & 31, h = ln >> 5;
        f32x4 v0, v1;
        #pragma unroll
        for (int ks = 0; ks < 4; ++ks) {
          v0[ks] = lt[ml][js * 8 + 2 * ks + h];
          v1[ks] = lt[32 + ml][js * 8 + 2 * ks + h];
        }
        size_t off = ((size_t)(g * 128 + sh + c8 * 8 + js) * 64 + ln) * 8;
        *(f32x4*)(thw + off)     = v0;
        *(f32x4*)(thw + off + 4) = v1;
      }
    }
    return;
  }
  // ---- Bt + bias branch
  __shared__ float tile[32][292];
  const int i0 = (bid >> 5) * 32, o0 = (bid & 31) * 32;
  {
    const int r = tid >> 3, seg = tid & 7;
    const float* src = C + (size_t)(i0 + r) * 9216 + (size_t)o0 * 9 + seg * 36;
    float* dst = &tile[r][seg * 36];
    #pragma unroll
    for (int v = 0; v < 9; ++v) *(f32x4*)(dst + v * 4) = *(const f32x4*)(src + v * 4);
  }
  __syncthreads();
  #pragma unroll
  for (int j = 0; j < 4; ++j) {
    int e = tid + 256 * j;
    int il = e >> 5, ol = e & 31;
    int i = i0 + il, o = o0 + ol;
    bf16x8 v;
    #pragma unroll
    for (int d = 0; d < 8; ++d) v[d] = (bf16)tile[il][ol * 9 + 1 + d];
    size_t idx16 = (((size_t)(o >> 6) * 128 + (i >> 3)) * 8 + (i & 7)) * 64 + (o & 63);
    *(bf16x8*)&Bt[idx16 * 8] = v;
  }
  if (tid < 32) {
    float s = 0.f;
    #pragma unroll
    for (int i = 0; i < 32; ++i) s += tile[i][tid * 9];
    bias_p[(size_t)(bid >> 5) * 1024 + o0 + tid] = s;   // partial, no atomics
  }
}

// ---- fused basis-gen + GEMM: block 128x64, 4 waves (2wm x 2wn) of 64x32, grid 1024 ----
__global__ __launch_bounds__(256, 4)
void cheby_gemm(const float* __restrict__ thw, const bf16* __restrict__ Bt,
                const float* __restrict__ bias_p, float* __restrict__ out) {
  __shared__ bf16 Bs[2][4096];                     // 2 x 8 KB: [c 0..8)][col 0..64)][8]

  const int tid  = threadIdx.x;
  const int lane = tid & 63, w = tid >> 6;
  const int ml = lane & 31, h = lane >> 5;
  const int wm = w >> 1, wn = w & 1;
  const int nb = blockIdx.x & 15, mb = blockIdx.x >> 4;
  const int g  = mb * 2 + wm;                      // 64-row group of this wave
  const int o0 = nb * 64 + wn * 32;

  // seeds: coalesced dwordx4 pair per stage (R8 layout)
  const float* sp = thw + ((size_t)g * 128 * 64 + lane) * 8;       // + s*512 floats
  // B staging: wave w owns c-chunks {2w, 2w+1}; 1 KB each, contiguous
  const bf16* btw = Bt + (((size_t)nb * 128 * 8 + 2 * w) * 64 + lane) * 8;

  f32x16 acc[2];
  #pragma unroll
  for (int a = 0; a < 2; ++a)
    #pragma unroll
    for (int r = 0; r < 16; ++r) acc[a][r] = 0.f;

  f32x4 sa[4], sb[4];                              // seed slots: stage s -> slot s&3

  // prologue: seeds(0),(1); B(0) -> buf 0
  sa[0] = *(const f32x4*)(sp);       sb[0] = *(const f32x4*)(sp + 4);
  sa[1] = *(const f32x4*)(sp + 512); sb[1] = *(const f32x4*)(sp + 516);
  g2lds16(btw,       &Bs[0][(2 * w) * 512]);
  g2lds16(btw + 512, &Bs[0][(2 * w + 1) * 512]);

  #pragma unroll 1
  for (int s4 = 0; s4 < 128; s4 += 4) {
    #pragma unroll
    for (int u = 0; u < 4; ++u) {
      const int s = s4 + u, bi = u & 1;
      __syncthreads();                             // Bs[bi] landed; Bs[bi^1] free
      if (s < 127) {                               // stage s+1 -> other buffer
        const bf16* gsrc = btw + (size_t)(s + 1) * 4096;
        g2lds16(gsrc,       &Bs[bi ^ 1][(2 * w) * 512]);
        g2lds16(gsrc + 512, &Bs[bi ^ 1][(2 * w + 1) * 512]);
      }
      {                                            // seeds for s+2 -> slot (u+2)&3
        const int sl = (s + 2 < 127) ? s + 2 : 127;
        sa[(u + 2) & 3] = *(const f32x4*)(sp + (size_t)sl * 512);
        sb[(u + 2) & 3] = *(const f32x4*)(sp + (size_t)sl * 512 + 4);
      }
      // gen A-frags from slot u (loaded 2 stages ago): stride-2 packed chains
      bf16x8 afr[2][4];
      #pragma unroll
      for (int r = 0; r < 2; ++r) {
        const f32x4 sd = r ? sb[u] : sa[u];
        #pragma unroll
        for (int ks = 0; ks < 4; ++ks) {
          const float t  = sd[ks];
          const float T2 = __builtin_fmaf(t + t, t, -1.f);   // T_2 = 2t^2-1
          const float c2 = T2 + T2;
          const f32x2 c2v = {c2, c2};
          f32x2 pm1 = {t, 1.f};                    // (T_-1, T_0)
          f32x2 p   = {t, T2};                     // (T_1, T_2)
          #pragma unroll
          for (int j2 = 0; j2 < 4; ++j2) {         // dword j2 = (T_{2j2+1}, T_{2j2+2})
            afr[r][ks][2 * j2]     = (bf16)p.x;
            afr[r][ks][2 * j2 + 1] = (bf16)p.y;
            f32x2 pn = c2v * p - pm1;              // pk_fma
            pm1 = p; p = pn;
          }
        }
      }
      // B frags + MFMA: 4 ks x 2 mt of 32x32x16
      #pragma unroll
      for (int ks = 0; ks < 4; ++ks) {
        bf16x8 bf = *(const bf16x8*)&Bs[bi][((ks * 2 + h) * 64 + wn * 32 + ml) * 8];
        acc[0] = __builtin_amdgcn_mfma_f32_32x32x16_bf16(afr[0][ks], bf, acc[0], 0, 0, 0);
        acc[1] = __builtin_amdgcn_mfma_f32_32x32x16_bf16(afr[1][ks], bf, acc[1], 0, 0, 0);
      }
    }
  }

  // epilogue: bias from partials; 32x32 C/D layout col=lane&31, row=(reg&3)+8*(reg>>2)+4*h
  const int c0 = nb * 64 + wn * 32 + ml;
  float bv = 0.f;
  #pragma unroll
  for (int p = 0; p < 32; ++p) bv += bias_p[(size_t)p * 1024 + c0];
  #pragma unroll
  for (int mt = 0; mt < 2; ++mt)
    #pragma unroll
    for (int r = 0; r < 16; ++r) {
      int row = g * 64 + mt * 32 + (r & 3) + 8 * (r >> 2) + 4 * h;
      out[(size_t)row * 1024 + c0] = acc[mt][r] + bv;
    }
  (void)o0;
}

// ---- fallback (ws too small) — correct, slow, should never run
__global__ __launch_bounds__(256)
void cheby_naive(const float* __restrict__ x, const float* __restrict__ C,
                 float* __restrict__ out) {
  const int t = blockIdx.x, tid = threadIdx.x;
  float acc[4] = {0.f, 0.f, 0.f, 0.f};
  for (int i = 0; i < 1024; ++i) {
    float th = tanhf(x[(size_t)t * 1024 + i]);
    float T[9]; T[0] = 1.f; T[1] = th;
    #pragma unroll
    for (int d = 2; d < 9; ++d) T[d] = 2.f * th * T[d - 1] - T[d - 2];
    #pragma unroll
    for (int j = 0; j < 4; ++j) {
      const float* cp = &C[((size_t)i * 1024 + tid + j * 256) * 9];
      float s = 0.f;
      #pragma unroll
      for (int d = 0; d < 9; ++d) s += T[d] * cp[d];
      acc[j] += s;
    }
  }
  #pragma unroll
  for (int j = 0; j < 4; ++j) out[(size_t)t * 1024 + tid + j * 256] = acc[j];
}

extern "C" void kernel_launch(void* const* d_in, const int* in_sizes, int n_in,
                              void* d_out, int out_size, void* d_ws, size_t ws_size,
                              hipStream_t stream) {
  (void)in_sizes; (void)n_in; (void)out_size;
  const float* x = (const float*)d_in[0];
  const float* C = (const float*)d_in[1];
  float* out = (float*)d_out;

  const size_t bt_bytes = (size_t)1024 * 8192 * sizeof(bf16);   // 16.78 MB
  const size_t bp_bytes = (size_t)32 * 1024 * sizeof(float);    // 128 KB
  const size_t th_bytes = (size_t)8192 * 1024 * sizeof(float);  // 33.55 MB

  if (ws_size >= bt_bytes + bp_bytes + th_bytes) {
    bf16*  Bt     = (bf16*)d_ws;
    float* bias_p = (float*)((char*)d_ws + bt_bytes);
    float* thw    = (float*)((char*)d_ws + bt_bytes + bp_bytes);
    cheby_prep<<<1280, 256, 0, stream>>>(x, C, Bt, bias_p, thw);
    cheby_gemm<<<1024, 256, 0, stream>>>(thw, Bt, bias_p, out);
  } else {
    cheby_naive<<<8192, 256, 0, stream>>>(x, C, out);
  }
}